// Round 1
// baseline (2532.754 us; speedup 1.0000x reference)
//
#include <hip/hip_runtime.h>
#include <math.h>

#define BN 512
#define DN 256
#define KN 65536
#define CN 1000
#define EQ_CAP 256
#define DCS 16   // k-splits for dc gemm
#define DKC 32   // k chunk staged in LDS

__device__ __forceinline__ unsigned fkey(float f) {
    unsigned b = __float_as_uint(f);
    return (b & 0x80000000u) ? ~b : (b | 0x80000000u);
}

// ---------------- GEMM: A[512,256] @ Q[256,65536] -> out[512,65536] ----------------
// block: 256 thr, tile 64b x 128k. thread: 8 b-rows x 4 consecutive k (float4).
__global__ void __launch_bounds__(256) gemm_aq(const float* __restrict__ A,
                                               const float* __restrict__ Q,
                                               float* __restrict__ out) {
    __shared__ __align__(16) float As[64 * 256];  // 64 KB
    int tid = threadIdx.x;
    int k0 = blockIdx.x * 128;
    int b0 = blockIdx.y * 64;
    // stage A tile (64 rows x 256 d) — coalesced float4
    #pragma unroll
    for (int c = 0; c < 16; ++c) {
        int flat = c * 1024 + tid * 4;
        *(float4*)&As[flat] = *(const float4*)&A[b0 * DN + flat];
    }
    __syncthreads();
    int kk = tid & 31;   // 32 k-groups * 4 = 128 k
    int bb = tid >> 5;   // 8 b-groups * 8 rows = 64 b
    float acc[8][4];
    #pragma unroll
    for (int r = 0; r < 8; ++r)
        #pragma unroll
        for (int j = 0; j < 4; ++j) acc[r][j] = 0.f;
    const float* qb = Q + k0 + kk * 4;
    for (int d = 0; d < DN; d += 4) {
        float4 q0 = *(const float4*)&qb[(size_t)(d + 0) * KN];
        float4 q1 = *(const float4*)&qb[(size_t)(d + 1) * KN];
        float4 q2 = *(const float4*)&qb[(size_t)(d + 2) * KN];
        float4 q3 = *(const float4*)&qb[(size_t)(d + 3) * KN];
        #pragma unroll
        for (int r = 0; r < 8; ++r) {
            float4 a = *(const float4*)&As[(bb * 8 + r) * 256 + d];
            acc[r][0] = fmaf(a.w, q3.x, fmaf(a.z, q2.x, fmaf(a.y, q1.x, fmaf(a.x, q0.x, acc[r][0]))));
            acc[r][1] = fmaf(a.w, q3.y, fmaf(a.z, q2.y, fmaf(a.y, q1.y, fmaf(a.x, q0.y, acc[r][1]))));
            acc[r][2] = fmaf(a.w, q3.z, fmaf(a.z, q2.z, fmaf(a.y, q1.z, fmaf(a.x, q0.z, acc[r][2]))));
            acc[r][3] = fmaf(a.w, q3.w, fmaf(a.z, q2.w, fmaf(a.y, q1.w, fmaf(a.x, q0.w, acc[r][3]))));
        }
    }
    #pragma unroll
    for (int r = 0; r < 8; ++r) {
        int b = b0 + bb * 8 + r;
        float4 v = make_float4(acc[r][0], acc[r][1], acc[r][2], acc[r][3]);
        *(float4*)&out[(size_t)b * KN + k0 + kk * 4] = v;
    }
}

// ---------------- supcon: per-row radix-select top-200 + masked softmax sum ----------------
__global__ void __launch_bounds__(256) supcon(const float* __restrict__ sim,
                                              const int* __restrict__ qlabel,
                                              const int* __restrict__ target,
                                              const int* __restrict__ knnp,
                                              float* __restrict__ out0) {
    __shared__ unsigned hist[256];
    __shared__ unsigned s_prefix, s_cntAbove;
    __shared__ int eqIdx[EQ_CAP];
    __shared__ unsigned eqCount;
    __shared__ float redZ[256], redN[256];
    int tid = threadIdx.x;
    int row = blockIdx.x;
    const float* srow = sim + (size_t)row * KN;
    int knn = *knnp;
    int tgt = target[row];
    if (tid == 0) { s_prefix = 0u; s_cntAbove = 0u; eqCount = 0u; }
    __syncthreads();
    for (int p = 0; p < 4; ++p) {
        int shift = 24 - 8 * p;
        hist[tid] = 0u;
        __syncthreads();
        unsigned prefix = s_prefix;
        for (int i = tid; i < KN; i += 256) {
            unsigned u = fkey(srow[i]);
            if (p == 0 || (u >> (shift + 8)) == prefix)
                atomicAdd(&hist[(u >> shift) & 255u], 1u);
        }
        __syncthreads();
        if (tid == 0) {
            unsigned acc = s_cntAbove;
            int chosen = 0;
            for (int bin = 255; bin >= 0; --bin) {
                if (acc + hist[bin] >= (unsigned)knn) { chosen = bin; break; }
                acc += hist[bin];
            }
            s_cntAbove = acc;
            s_prefix = (prefix << 8) | (unsigned)chosen;
        }
        __syncthreads();
    }
    unsigned tu = s_prefix;
    unsigned cgt = s_cntAbove;   // count strictly greater than threshold key
    const float invT = 1.0f / 0.07f;
    float Zl = 0.f, Nl = 0.f;
    for (int i = tid; i < KN; i += 256) {
        float f = srow[i];
        unsigned u = fkey(f);
        if (u > tu) {
            float e = __expf(f * invT);
            Zl += e;
            if (qlabel[i] == tgt) Nl += e;
        } else if (u == tu) {
            unsigned pos = atomicAdd(&eqCount, 1u);
            if (pos < EQ_CAP) eqIdx[pos] = i;
        }
    }
    redZ[tid] = Zl; redN[tid] = Nl;
    __syncthreads();
    for (int s = 128; s > 0; s >>= 1) {
        if (tid < s) { redZ[tid] += redZ[tid + s]; redN[tid] += redN[tid + s]; }
        __syncthreads();
    }
    if (tid == 0) {
        float Z = redZ[0], num = redN[0];
        int neq = (int)(eqCount < (unsigned)EQ_CAP ? eqCount : (unsigned)EQ_CAP);
        int needed = knn - (int)cgt;
        if (needed > neq) needed = neq;
        // ties: include lowest indices first (lax.top_k tie-break)
        for (int a = 1; a < neq; ++a) {
            int v = eqIdx[a]; int b2 = a - 1;
            while (b2 >= 0 && eqIdx[b2] > v) { eqIdx[b2 + 1] = eqIdx[b2]; --b2; }
            eqIdx[b2 + 1] = v;
        }
        if (neq > 0) {
            float w = __expf(srow[eqIdx[0]] * invT);
            for (int a = 0; a < needed; ++a) {
                Z += w;
                if (qlabel[eqIdx[a]] == tgt) num += w;
            }
        }
        float gt = num / Z;
        if (gt > 1e-8f) atomicAdd(out0, -logf(gt) * (1.0f / (float)BN));
    }
}

// ---------------- exp((x)/0.1) in place + row sums ----------------
__global__ void __launch_bounds__(256) exp_z(float* __restrict__ Ebuf, float* __restrict__ Z) {
    int row = blockIdx.y;
    int idx = (blockIdx.x * 256 + threadIdx.x) * 4;
    size_t base = (size_t)row * KN + idx;
    float4 v = *(float4*)&Ebuf[base];
    v.x = __expf(v.x * 10.0f); v.y = __expf(v.y * 10.0f);
    v.z = __expf(v.z * 10.0f); v.w = __expf(v.w * 10.0f);
    *(float4*)&Ebuf[base] = v;
    float s = v.x + v.y + v.z + v.w;
    for (int off = 32; off > 0; off >>= 1) s += __shfl_down(s, off, 64);
    __shared__ float red[4];
    int wid = threadIdx.x >> 6;
    if ((threadIdx.x & 63) == 0) red[wid] = s;
    __syncthreads();
    if (threadIdx.x == 0) atomicAdd(&Z[row], red[0] + red[1] + red[2] + red[3]);
}

// ---------------- dc gemm: E[512,64k] @ P[1000,64k]^T -> dct[512,1024] (raw, split-k) ----------------
__global__ void __launch_bounds__(256) dc_gemm(const float* __restrict__ E,
                                               const float* __restrict__ P,
                                               float* __restrict__ dct) {
    __shared__ __align__(16) float Es[128 * 36];
    __shared__ __align__(16) float Ps[128 * 36];
    int tid = threadIdx.x;
    int c0 = blockIdx.x * 128;
    int b0 = blockIdx.y * 128;
    int kb = blockIdx.z * (KN / DCS);
    int tx = tid & 15, ty = tid >> 4;
    float acc[8][8];
    #pragma unroll
    for (int r = 0; r < 8; ++r)
        #pragma unroll
        for (int j = 0; j < 8; ++j) acc[r][j] = 0.f;
    for (int kc = 0; kc < KN / DCS; kc += DKC) {
        #pragma unroll
        for (int c = 0; c < 4; ++c) {
            int flat = c * 1024 + tid * 4;
            int i = flat >> 5, kq = flat & 31;
            *(float4*)&Es[i * 36 + kq] =
                *(const float4*)&E[(size_t)(b0 + i) * KN + kb + kc + kq];
        }
        #pragma unroll
        for (int c = 0; c < 4; ++c) {
            int flat = c * 1024 + tid * 4;
            int i = flat >> 5, kq = flat & 31;
            int cr = c0 + i;
            float4 v = make_float4(0.f, 0.f, 0.f, 0.f);
            if (cr < CN) v = *(const float4*)&P[(size_t)cr * KN + kb + kc + kq];
            *(float4*)&Ps[i * 36 + kq] = v;
        }
        __syncthreads();
        #pragma unroll
        for (int kq = 0; kq < DKC; kq += 4) {
            float4 av[8], pv[8];
            #pragma unroll
            for (int r = 0; r < 8; ++r) av[r] = *(float4*)&Es[(ty + 16 * r) * 36 + kq];
            #pragma unroll
            for (int j = 0; j < 8; ++j) pv[j] = *(float4*)&Ps[(tx + 16 * j) * 36 + kq];
            #pragma unroll
            for (int r = 0; r < 8; ++r)
                #pragma unroll
                for (int j = 0; j < 8; ++j) {
                    acc[r][j] = fmaf(av[r].x, pv[j].x, acc[r][j]);
                    acc[r][j] = fmaf(av[r].y, pv[j].y, acc[r][j]);
                    acc[r][j] = fmaf(av[r].z, pv[j].z, acc[r][j]);
                    acc[r][j] = fmaf(av[r].w, pv[j].w, acc[r][j]);
                }
        }
        __syncthreads();
    }
    #pragma unroll
    for (int r = 0; r < 8; ++r) {
        int b = b0 + ty + 16 * r;
        #pragma unroll
        for (int j = 0; j < 8; ++j) {
            int cc = c0 + tx + 16 * j;
            if (cc < CN) atomicAdd(&dct[b * 1024 + cc], acc[r][j]);
        }
    }
}

// ---------------- log_softmax(q_logits), qmask, fc loss ----------------
__global__ void __launch_bounds__(256) logq_fc(const float* __restrict__ x_all,
                                               const int* __restrict__ target,
                                               float* __restrict__ logq,
                                               float* __restrict__ qmask,
                                               float* __restrict__ out1) {
    int row = blockIdx.x, tid = threadIdx.x;
    const float* x = x_all + (size_t)row * CN;
    __shared__ float red[256], red2[256];
    float mx = -INFINITY, mn = INFINITY;
    for (int c = tid; c < CN; c += 256) { float v = x[c]; mx = fmaxf(mx, v); mn = fminf(mn, v); }
    red[tid] = mx; red2[tid] = mn;
    __syncthreads();
    for (int s = 128; s > 0; s >>= 1) {
        if (tid < s) { red[tid] = fmaxf(red[tid], red[tid + s]); red2[tid] = fminf(red2[tid], red2[tid + s]); }
        __syncthreads();
    }
    mx = red[0]; mn = red2[0];
    __syncthreads();
    float se = 0.f, sx = 0.f;
    for (int c = tid; c < CN; c += 256) { float v = x[c]; se += __expf(v - mx); sx += v; }
    red[tid] = se; red2[tid] = sx;
    __syncthreads();
    for (int s = 128; s > 0; s >>= 1) {
        if (tid < s) { red[tid] += red[tid + s]; red2[tid] += red2[tid + s]; }
        __syncthreads();
    }
    float lse = mx + logf(red[0]);
    float sumlogq = red2[0] - (float)CN * lse;
    for (int c = tid; c < CN; c += 256) logq[(size_t)row * CN + c] = x[c] - lse;
    if (tid == 0) {
        float lqt = x[target[row]] - lse;
        bool qm = (mn - lse) > logf(1e-8f);
        qmask[row] = qm ? 1.0f : 0.0f;
        if (qm) {
            float fc = -(0.1f / 999.0f * (sumlogq - lqt) + 0.9f * lqt);
            atomicAdd(out1, fc * (1.0f / (float)BN));
        }
    }
}

// ---------------- dc loss: KL(dct/Z || softmax(q_logits)) masked ----------------
__global__ void __launch_bounds__(256) dc_loss(const float* __restrict__ dct,
                                               const float* __restrict__ logq,
                                               const float* __restrict__ qmask,
                                               const float* __restrict__ Z,
                                               float* __restrict__ out2) {
    int row = blockIdx.x, tid = threadIdx.x;
    __shared__ float red[256];
    float invZ = 1.0f / Z[row];
    float s = 0.f;
    for (int c = tid; c < CN; c += 256) {
        float T = dct[row * 1024 + c] * invZ;
        if (T > 0.f) s += T * (logf(T) - logq[(size_t)row * CN + c]);
    }
    red[tid] = s;
    __syncthreads();
    for (int st = 128; st > 0; st >>= 1) {
        if (tid < st) red[tid] += red[tid + st];
        __syncthreads();
    }
    if (tid == 0 && qmask[row] > 0.f)
        atomicAdd(out2, red[0] * (1.0f / (float)BN));
}

extern "C" void kernel_launch(void* const* d_in, const int* in_sizes, int n_in,
                              void* d_out, int out_size, void* d_ws, size_t ws_size,
                              hipStream_t stream) {
    (void)in_sizes; (void)n_in; (void)out_size; (void)ws_size;
    const float* norm_q   = (const float*)d_in[0];
    const float* q_logits = (const float*)d_in[1];
    const float* k_feat   = (const float*)d_in[2];
    // d_in[3] = logits_k (unused by reference)
    const float* queue    = (const float*)d_in[4];
    const float* qlp      = (const float*)d_in[5];
    const int*   qlabel   = (const int*)d_in[6];
    const int*   target   = (const int*)d_in[7];
    const int*   knnp     = (const int*)d_in[8];
    float* out = (float*)d_out;

    char* ws = (char*)d_ws;
    float* simE  = (float*)ws;                                  // 512*65536 f32 = 128 MB
    float* dct   = (float*)(ws + 134217728);                    // 512*1024  f32 = 2 MB
    float* Zb    = (float*)(ws + 134217728 + 2097152);          // 512 f32
    float* logq  = (float*)(ws + 134217728 + 2097152 + 2048);   // 512*1000 f32
    float* qmask = (float*)(ws + 134217728 + 2097152 + 2048 + 2048000); // 512 f32

    hipMemsetAsync(dct, 0, 2097152 + 2048, stream);  // dct + Zb
    hipMemsetAsync(d_out, 0, 3 * sizeof(float), stream);

    // supcon path: sim = norm_q @ queue, then top-k loss
    gemm_aq<<<dim3(KN / 128, BN / 64), 256, 0, stream>>>(norm_q, queue, simE);
    supcon<<<dim3(BN), 256, 0, stream>>>(simE, qlabel, target, knnp, out + 0);
    // dc path: reuse simE buffer for k_feat @ queue, exp in place, raw gemm
    gemm_aq<<<dim3(KN / 128, BN / 64), 256, 0, stream>>>(k_feat, queue, simE);
    exp_z<<<dim3(KN / 1024, BN), 256, 0, stream>>>(simE, Zb);
    dc_gemm<<<dim3(8, 4, DCS), 256, 0, stream>>>(simE, qlp, dct);
    // fc path + dc loss
    logq_fc<<<dim3(BN), 256, 0, stream>>>(q_logits, target, logq, qmask, out + 1);
    dc_loss<<<dim3(BN), 256, 0, stream>>>(dct, logq, qmask, Zb, out + 2);
}

// Round 2
// 1008.142 us; speedup vs baseline: 2.5123x; 2.5123x over previous
//
#include <hip/hip_runtime.h>
#include <math.h>

#define BN 512
#define DN 256
#define KN 65536
#define CN 1000
#define EQ_CAP 512

typedef __attribute__((ext_vector_type(8))) short bf16x8;
typedef __attribute__((ext_vector_type(4))) float f32x4;

__device__ __forceinline__ unsigned short f2bf(float f) {
    unsigned u = __float_as_uint(f);
    unsigned r = (u + 0x7FFFu + ((u >> 16) & 1u)) >> 16;
    return (unsigned short)r;
}
__device__ __forceinline__ float bf2f(unsigned short h) {
    return __uint_as_float(((unsigned)h) << 16);
}
__device__ __forceinline__ unsigned fkey16(unsigned b) {
    b &= 0xFFFFu;
    return (b & 0x8000u) ? ((~b) & 0xFFFFu) : (b | 0x8000u);
}
__device__ __forceinline__ void async16(const void* g, void* l) {
    __builtin_amdgcn_global_load_lds(
        (const __attribute__((address_space(1))) unsigned*)g,
        (__attribute__((address_space(3))) unsigned*)l, 16, 0, 0);
}

// ---- tiny fp32 -> bf16 convert (norm_q / k_feat) ----
__global__ void __launch_bounds__(256) cvt_bf16(const float* __restrict__ in,
                                                unsigned short* __restrict__ out) {
    int i = (blockIdx.x * 256 + threadIdx.x) * 4;
    float4 v = *(const float4*)&in[i];
    ushort4 o;
    o.x = f2bf(v.x); o.y = f2bf(v.y); o.z = f2bf(v.z); o.w = f2bf(v.w);
    *(ushort4*)&out[i] = o;
}

// ---- queue [256,65536] f32 -> queueT [65536,256] bf16 ----
__global__ void __launch_bounds__(256) transpose_q(const float* __restrict__ Q,
                                                   unsigned short* __restrict__ Qt) {
    __shared__ float T[64][65];
    int tid = threadIdx.x;
    int n0 = blockIdx.x * 64;
    int d0 = blockIdx.y * 64;
    #pragma unroll
    for (int i = 0; i < 4; ++i) {
        int flat = i * 256 + tid;
        int d = flat >> 4, nq = (flat & 15) * 4;
        float4 v = *(const float4*)&Q[(size_t)(d0 + d) * KN + n0 + nq];
        T[d][nq] = v.x; T[d][nq + 1] = v.y; T[d][nq + 2] = v.z; T[d][nq + 3] = v.w;
    }
    __syncthreads();
    int n = tid >> 2, dbase = (tid & 3) * 16;
    unsigned u[8];
    #pragma unroll
    for (int j = 0; j < 8; ++j) {
        unsigned short a = f2bf(T[dbase + 2 * j][n]);
        unsigned short b = f2bf(T[dbase + 2 * j + 1][n]);
        u[j] = (unsigned)a | ((unsigned)b << 16);
    }
    unsigned short* o = &Qt[(size_t)(n0 + n) * DN + d0 + dbase];
    *(uint4*)o = make_uint4(u[0], u[1], u[2], u[3]);
    *(uint4*)(o + 8) = make_uint4(u[4], u[5], u[6], u[7]);
}

// ---- MFMA GEMM: A[512,256]bf16 @ QtT -> sim[512,65536]; EXPOUT fuses exp(10x)+rowsum ----
template <bool EXPOUT>
__global__ void __launch_bounds__(256) gemm_sim(const unsigned short* __restrict__ A,
                                                const unsigned short* __restrict__ Bt,
                                                unsigned short* __restrict__ outb,
                                                float* __restrict__ Zb) {
    __shared__ unsigned short As[128 * 32];
    __shared__ unsigned short Bs[128 * 32];
    int tid = threadIdx.x;
    int n0 = blockIdx.x * 128, m0 = blockIdx.y * 128;
    int lane = tid & 63, w = tid >> 6;
    int l15 = lane & 15, quad = lane >> 4;
    int wm = w & 1, wn = w >> 1;
    f32x4 acc[4][4];
    #pragma unroll
    for (int r = 0; r < 4; ++r)
        #pragma unroll
        for (int c = 0; c < 4; ++c)
            #pragma unroll
            for (int j = 0; j < 4; ++j) acc[r][c][j] = 0.f;
    for (int k0 = 0; k0 < DN; k0 += 32) {
        #pragma unroll
        for (int i = 0; i < 2; ++i) {
            int flat = (i * 256 + tid) * 8;
            int row = flat >> 5, kk = flat & 31;
            async16(A + (size_t)(m0 + row) * DN + k0 + kk, &As[flat]);
        }
        #pragma unroll
        for (int i = 0; i < 2; ++i) {
            int flat = (i * 256 + tid) * 8;
            int row = flat >> 5, kk = flat & 31;
            async16(Bt + (size_t)(n0 + row) * DN + k0 + kk, &Bs[flat]);
        }
        __syncthreads();
        bf16x8 af[4], bfr[4];
        #pragma unroll
        for (int r = 0; r < 4; ++r) af[r] = *(const bf16x8*)&As[(wm * 64 + r * 16 + l15) * 32 + quad * 8];
        #pragma unroll
        for (int c = 0; c < 4; ++c) bfr[c] = *(const bf16x8*)&Bs[(wn * 64 + c * 16 + l15) * 32 + quad * 8];
        #pragma unroll
        for (int r = 0; r < 4; ++r)
            #pragma unroll
            for (int c = 0; c < 4; ++c)
                acc[r][c] = __builtin_amdgcn_mfma_f32_16x16x32_bf16(af[r], bfr[c], acc[r][c], 0, 0, 0);
        __syncthreads();
    }
    #pragma unroll
    for (int r = 0; r < 4; ++r) {
        #pragma unroll
        for (int reg = 0; reg < 4; ++reg) {
            int m = m0 + wm * 64 + r * 16 + quad * 4 + reg;
            float rs = 0.f;
            #pragma unroll
            for (int c = 0; c < 4; ++c) {
                int n = n0 + wn * 64 + c * 16 + l15;
                float v = acc[r][c][reg];
                unsigned short us;
                if (EXPOUT) {
                    float e = __expf(v * 10.0f);
                    us = f2bf(e);
                    rs += bf2f(us);
                } else {
                    us = f2bf(v);
                }
                outb[(size_t)m * KN + n] = us;
            }
            if (EXPOUT) {
                #pragma unroll
                for (int off = 8; off; off >>= 1) rs += __shfl_xor(rs, off, 16);
                if (l15 == 0) atomicAdd(&Zb[m], rs);
            }
        }
    }
}

// ---- supcon on bf16 sim: 2-pass radix select over 16-bit keys + fused loss ----
__global__ void __launch_bounds__(256) supcon(const unsigned short* __restrict__ sim,
                                              const int* __restrict__ qlabel,
                                              const int* __restrict__ target,
                                              const int* __restrict__ knnp,
                                              float* __restrict__ out0) {
    __shared__ unsigned hist[4][256];
    __shared__ unsigned s_sel, s_cntAbove;
    __shared__ int eqIdx[EQ_CAP];
    __shared__ unsigned eqCount;
    __shared__ float redZ[256], redN[256];
    int tid = threadIdx.x, w = tid >> 6;
    int row = blockIdx.x;
    const unsigned short* srow = sim + (size_t)row * KN;
    int knn = *knnp;
    int tgt = target[row];
    if (tid == 0) { eqCount = 0u; }
    // pass 0: high byte
    #pragma unroll
    for (int j = 0; j < 4; ++j) hist[j][tid] = 0u;
    __syncthreads();
    for (int i0 = tid * 4; i0 < KN; i0 += 1024) {
        uint2 v = *(const uint2*)&srow[i0];
        atomicAdd(&hist[w][fkey16(v.x) >> 8], 1u);
        atomicAdd(&hist[w][fkey16(v.x >> 16) >> 8], 1u);
        atomicAdd(&hist[w][fkey16(v.y) >> 8], 1u);
        atomicAdd(&hist[w][fkey16(v.y >> 16) >> 8], 1u);
    }
    __syncthreads();
    if (tid == 0) {
        unsigned acc = 0; int chosen = 0;
        for (int bin = 255; bin >= 0; --bin) {
            unsigned h = hist[0][bin] + hist[1][bin] + hist[2][bin] + hist[3][bin];
            if (acc + h >= (unsigned)knn) { chosen = bin; break; }
            acc += h;
        }
        s_cntAbove = acc; s_sel = (unsigned)chosen;
    }
    __syncthreads();
    unsigned selHi = s_sel;
    // pass 1: low byte among keys with matching high byte
    #pragma unroll
    for (int j = 0; j < 4; ++j) hist[j][tid] = 0u;
    __syncthreads();
    for (int i0 = tid * 4; i0 < KN; i0 += 1024) {
        uint2 v = *(const uint2*)&srow[i0];
        unsigned k0 = fkey16(v.x), k1 = fkey16(v.x >> 16), k2 = fkey16(v.y), k3 = fkey16(v.y >> 16);
        if ((k0 >> 8) == selHi) atomicAdd(&hist[w][k0 & 255u], 1u);
        if ((k1 >> 8) == selHi) atomicAdd(&hist[w][k1 & 255u], 1u);
        if ((k2 >> 8) == selHi) atomicAdd(&hist[w][k2 & 255u], 1u);
        if ((k3 >> 8) == selHi) atomicAdd(&hist[w][k3 & 255u], 1u);
    }
    __syncthreads();
    if (tid == 0) {
        unsigned acc = s_cntAbove; int chosen = 0;
        for (int bin = 255; bin >= 0; --bin) {
            unsigned h = hist[0][bin] + hist[1][bin] + hist[2][bin] + hist[3][bin];
            if (acc + h >= (unsigned)knn) { chosen = bin; break; }
            acc += h;
        }
        s_cntAbove = acc; s_sel = (selHi << 8) | (unsigned)chosen;
    }
    __syncthreads();
    unsigned tu = s_sel;
    unsigned cgt = s_cntAbove;
    const float invT = 1.0f / 0.07f;
    float Zl = 0.f, Nl = 0.f;
    for (int i0 = tid * 4; i0 < KN; i0 += 1024) {
        uint2 v = *(const uint2*)&srow[i0];
        unsigned bits[4] = {v.x & 0xFFFFu, v.x >> 16, v.y & 0xFFFFu, v.y >> 16};
        #pragma unroll
        for (int j = 0; j < 4; ++j) {
            unsigned u = fkey16(bits[j]);
            if (u > tu) {
                float e = __expf(bf2f((unsigned short)bits[j]) * invT);
                Zl += e;
                if (qlabel[i0 + j] == tgt) Nl += e;
            } else if (u == tu) {
                unsigned pos = atomicAdd(&eqCount, 1u);
                if (pos < EQ_CAP) eqIdx[pos] = i0 + j;
            }
        }
    }
    redZ[tid] = Zl; redN[tid] = Nl;
    __syncthreads();
    for (int s = 128; s > 0; s >>= 1) {
        if (tid < s) { redZ[tid] += redZ[tid + s]; redN[tid] += redN[tid + s]; }
        __syncthreads();
    }
    if (tid == 0) {
        float Z = redZ[0], num = redN[0];
        int neq = (int)(eqCount < (unsigned)EQ_CAP ? eqCount : (unsigned)EQ_CAP);
        int needed = knn - (int)cgt;
        if (needed > neq) needed = neq;
        for (int a = 1; a < neq; ++a) {
            int v = eqIdx[a]; int b2 = a - 1;
            while (b2 >= 0 && eqIdx[b2] > v) { eqIdx[b2 + 1] = eqIdx[b2]; --b2; }
            eqIdx[b2 + 1] = v;
        }
        unsigned tb = (tu & 0x8000u) ? (tu & 0x7FFFu) : ((~tu) & 0xFFFFu);
        float wt = __expf(bf2f((unsigned short)tb) * invT);
        for (int a = 0; a < needed; ++a) {
            Z += wt;
            if (qlabel[eqIdx[a]] == tgt) num += wt;
        }
        float gt = num / Z;
        if (gt > 1e-8f) atomicAdd(out0, -logf(gt) * (1.0f / (float)BN));
    }
}

// ---- dc gemm: E[512,65536]bf16 @ qlp[1000,65536]f32(->bf16) ^T, split-k=16, atomic f32 ----
__global__ void __launch_bounds__(256) dc_gemm(const unsigned short* __restrict__ E,
                                               const float* __restrict__ P,
                                               float* __restrict__ dct) {
    __shared__ unsigned short As[128 * 32];
    __shared__ unsigned short Bs[128 * 32];
    int tid = threadIdx.x;
    int c0 = blockIdx.x * 128, m0 = blockIdx.y * 128;
    int kb = blockIdx.z * (KN / 16);
    int lane = tid & 63, w = tid >> 6;
    int l15 = lane & 15, quad = lane >> 4;
    int wm = w & 1, wn = w >> 1;
    int crow = tid >> 1, khalf = (tid & 1) * 16;
    bool cvalid = (c0 + crow) < CN;
    const float* pbase = P + (size_t)(c0 + crow) * KN + khalf;
    f32x4 acc[4][4];
    #pragma unroll
    for (int r = 0; r < 4; ++r)
        #pragma unroll
        for (int c = 0; c < 4; ++c)
            #pragma unroll
            for (int j = 0; j < 4; ++j) acc[r][c][j] = 0.f;
    for (int kc = 0; kc < KN / 16; kc += 32) {
        int k0 = kb + kc;
        #pragma unroll
        for (int i = 0; i < 2; ++i) {
            int flat = (i * 256 + tid) * 8;
            int row = flat >> 5, kk = flat & 31;
            async16(E + (size_t)(m0 + row) * KN + k0 + kk, &As[flat]);
        }
        float4 p0 = make_float4(0.f, 0.f, 0.f, 0.f), p1 = p0, p2 = p0, p3 = p0;
        if (cvalid) {
            p0 = *(const float4*)&pbase[k0];
            p1 = *(const float4*)&pbase[k0 + 4];
            p2 = *(const float4*)&pbase[k0 + 8];
            p3 = *(const float4*)&pbase[k0 + 12];
        }
        unsigned u0 = (unsigned)f2bf(p0.x) | ((unsigned)f2bf(p0.y) << 16);
        unsigned u1 = (unsigned)f2bf(p0.z) | ((unsigned)f2bf(p0.w) << 16);
        unsigned u2 = (unsigned)f2bf(p1.x) | ((unsigned)f2bf(p1.y) << 16);
        unsigned u3 = (unsigned)f2bf(p1.z) | ((unsigned)f2bf(p1.w) << 16);
        unsigned u4 = (unsigned)f2bf(p2.x) | ((unsigned)f2bf(p2.y) << 16);
        unsigned u5 = (unsigned)f2bf(p2.z) | ((unsigned)f2bf(p2.w) << 16);
        unsigned u6 = (unsigned)f2bf(p3.x) | ((unsigned)f2bf(p3.y) << 16);
        unsigned u7 = (unsigned)f2bf(p3.z) | ((unsigned)f2bf(p3.w) << 16);
        *(uint4*)&Bs[crow * 32 + khalf] = make_uint4(u0, u1, u2, u3);
        *(uint4*)&Bs[crow * 32 + khalf + 8] = make_uint4(u4, u5, u6, u7);
        __syncthreads();
        bf16x8 af[4], bfr[4];
        #pragma unroll
        for (int r = 0; r < 4; ++r) af[r] = *(const bf16x8*)&As[(wm * 64 + r * 16 + l15) * 32 + quad * 8];
        #pragma unroll
        for (int c = 0; c < 4; ++c) bfr[c] = *(const bf16x8*)&Bs[(wn * 64 + c * 16 + l15) * 32 + quad * 8];
        #pragma unroll
        for (int r = 0; r < 4; ++r)
            #pragma unroll
            for (int c = 0; c < 4; ++c)
                acc[r][c] = __builtin_amdgcn_mfma_f32_16x16x32_bf16(af[r], bfr[c], acc[r][c], 0, 0, 0);
        __syncthreads();
    }
    #pragma unroll
    for (int r = 0; r < 4; ++r)
        #pragma unroll
        for (int reg = 0; reg < 4; ++reg) {
            int m = m0 + wm * 64 + r * 16 + quad * 4 + reg;
            #pragma unroll
            for (int c = 0; c < 4; ++c) {
                int cc = c0 + wn * 64 + c * 16 + l15;
                atomicAdd(&dct[m * 1024 + cc], acc[r][c][reg]);
            }
        }
}

// ---- log_softmax(q_logits), qmask, fc loss ----
__global__ void __launch_bounds__(256) logq_fc(const float* __restrict__ x_all,
                                               const int* __restrict__ target,
                                               float* __restrict__ logq,
                                               float* __restrict__ qmask,
                                               float* __restrict__ out1) {
    int row = blockIdx.x, tid = threadIdx.x;
    const float* x = x_all + (size_t)row * CN;
    __shared__ float red[256], red2[256];
    float mx = -INFINITY, mn = INFINITY;
    for (int c = tid; c < CN; c += 256) { float v = x[c]; mx = fmaxf(mx, v); mn = fminf(mn, v); }
    red[tid] = mx; red2[tid] = mn;
    __syncthreads();
    for (int s = 128; s > 0; s >>= 1) {
        if (tid < s) { red[tid] = fmaxf(red[tid], red[tid + s]); red2[tid] = fminf(red2[tid], red2[tid + s]); }
        __syncthreads();
    }
    mx = red[0]; mn = red2[0];
    __syncthreads();
    float se = 0.f, sx = 0.f;
    for (int c = tid; c < CN; c += 256) { float v = x[c]; se += __expf(v - mx); sx += v; }
    red[tid] = se; red2[tid] = sx;
    __syncthreads();
    for (int s = 128; s > 0; s >>= 1) {
        if (tid < s) { red[tid] += red[tid + s]; red2[tid] += red2[tid + s]; }
        __syncthreads();
    }
    float lse = mx + logf(red[0]);
    float sumlogq = red2[0] - (float)CN * lse;
    for (int c = tid; c < CN; c += 256) logq[(size_t)row * CN + c] = x[c] - lse;
    if (tid == 0) {
        float lqt = x[target[row]] - lse;
        bool qm = (mn - lse) > logf(1e-8f);
        qmask[row] = qm ? 1.0f : 0.0f;
        if (qm) {
            float fc = -(0.1f / 999.0f * (sumlogq - lqt) + 0.9f * lqt);
            atomicAdd(out1, fc * (1.0f / (float)BN));
        }
    }
}

// ---- dc loss ----
__global__ void __launch_bounds__(256) dc_loss(const float* __restrict__ dct,
                                               const float* __restrict__ logq,
                                               const float* __restrict__ qmask,
                                               const float* __restrict__ Z,
                                               float* __restrict__ out2) {
    int row = blockIdx.x, tid = threadIdx.x;
    __shared__ float red[256];
    float invZ = 1.0f / Z[row];
    float s = 0.f;
    for (int c = tid; c < CN; c += 256) {
        float T = dct[row * 1024 + c] * invZ;
        if (T > 0.f) s += T * (logf(T) - logq[(size_t)row * CN + c]);
    }
    red[tid] = s;
    __syncthreads();
    for (int st = 128; st > 0; st >>= 1) {
        if (tid < st) red[tid] += red[tid + st];
        __syncthreads();
    }
    if (tid == 0 && qmask[row] > 0.f)
        atomicAdd(out2, red[0] * (1.0f / (float)BN));
}

extern "C" void kernel_launch(void* const* d_in, const int* in_sizes, int n_in,
                              void* d_out, int out_size, void* d_ws, size_t ws_size,
                              hipStream_t stream) {
    (void)in_sizes; (void)n_in; (void)out_size; (void)ws_size;
    const float* norm_q   = (const float*)d_in[0];
    const float* q_logits = (const float*)d_in[1];
    const float* k_feat   = (const float*)d_in[2];
    const float* queue    = (const float*)d_in[4];
    const float* qlp      = (const float*)d_in[5];
    const int*   qlabel   = (const int*)d_in[6];
    const int*   target   = (const int*)d_in[7];
    const int*   knnp     = (const int*)d_in[8];
    float* out = (float*)d_out;

    char* ws = (char*)d_ws;
    // layout (bytes): simBF/Ebf 64MiB | queueT 32MiB | nqb 256K | kfb 256K | dct 2MiB | Zb 2K | logq | qmask
    unsigned short* simBF  = (unsigned short*)(ws);                      // 67,108,864
    unsigned short* queueT = (unsigned short*)(ws + 67108864);           // 33,554,432
    unsigned short* nqb    = (unsigned short*)(ws + 100663296);          // 262,144
    unsigned short* kfb    = (unsigned short*)(ws + 100925440);          // 262,144
    float* dct   = (float*)(ws + 101187584);                             // 2,097,152
    float* Zb    = (float*)(ws + 103284736);                             // 2,048
    float* logq  = (float*)(ws + 103286784);                             // 2,048,000
    float* qmask = (float*)(ws + 105334784);                             // 2,048

    hipMemsetAsync(dct, 0, 2097152 + 2048, stream);   // dct + Zb
    hipMemsetAsync(d_out, 0, 3 * sizeof(float), stream);

    cvt_bf16<<<dim3(128), 256, 0, stream>>>(norm_q, nqb);
    cvt_bf16<<<dim3(128), 256, 0, stream>>>(k_feat, kfb);
    transpose_q<<<dim3(KN / 64, 4), 256, 0, stream>>>(queue, queueT);

    // supcon path
    gemm_sim<false><<<dim3(KN / 128, BN / 128), 256, 0, stream>>>(nqb, queueT, simBF, nullptr);
    supcon<<<dim3(BN), 256, 0, stream>>>(simBF, qlabel, target, knnp, out + 0);
    // dc path (E overlays simBF; exp + rowsum fused into gemm epilogue)
    gemm_sim<true><<<dim3(KN / 128, BN / 128), 256, 0, stream>>>(kfb, queueT, simBF, Zb);
    dc_gemm<<<dim3(8, 4, 16), 256, 0, stream>>>(simBF, qlp, dct);
    // fc + dc losses
    logq_fc<<<dim3(BN), 256, 0, stream>>>(q_logits, target, logq, qmask, out + 1);
    dc_loss<<<dim3(BN), 256, 0, stream>>>(dct, logq, qmask, Zb, out + 2);
}

// Round 3
// 800.889 us; speedup vs baseline: 3.1624x; 1.2588x over previous
//
#include <hip/hip_runtime.h>
#include <math.h>

#define BN 512
#define DN 256
#define KN 65536
#define CN 1000
#define EQ_CAP 512
#define EPSTR 136   // padded epilogue LDS stride (ushorts)

typedef __attribute__((ext_vector_type(8))) short bf16x8;
typedef __attribute__((ext_vector_type(4))) float f32x4;

__device__ __forceinline__ unsigned short f2bf(float f) {
    unsigned u = __float_as_uint(f);
    unsigned r = (u + 0x7FFFu + ((u >> 16) & 1u)) >> 16;
    return (unsigned short)r;
}
__device__ __forceinline__ float bf2f(unsigned short h) {
    return __uint_as_float(((unsigned)h) << 16);
}
__device__ __forceinline__ unsigned fkey16(unsigned b) {
    b &= 0xFFFFu;
    return (b & 0x8000u) ? ((~b) & 0xFFFFu) : (b | 0x8000u);
}
__device__ __forceinline__ void async16(const void* g, void* l) {
    __builtin_amdgcn_global_load_lds(
        (const __attribute__((address_space(1))) unsigned*)g,
        (__attribute__((address_space(3))) unsigned*)l, 16, 0, 0);
}

// ---- fp32 -> bf16 convert (norm_q / k_feat into Acat halves) ----
__global__ void __launch_bounds__(256) cvt_bf16(const float* __restrict__ in,
                                                unsigned short* __restrict__ out) {
    int i = (blockIdx.x * 256 + threadIdx.x) * 4;
    float4 v = *(const float4*)&in[i];
    ushort4 o;
    o.x = f2bf(v.x); o.y = f2bf(v.y); o.z = f2bf(v.z); o.w = f2bf(v.w);
    *(ushort4*)&out[i] = o;
}

// ---- queue [256,65536] f32 -> queueT [65536,256] bf16 ----
__global__ void __launch_bounds__(256) transpose_q(const float* __restrict__ Q,
                                                   unsigned short* __restrict__ Qt) {
    __shared__ float T[64][65];
    int tid = threadIdx.x;
    int n0 = blockIdx.x * 64;
    int d0 = blockIdx.y * 64;
    #pragma unroll
    for (int i = 0; i < 4; ++i) {
        int flat = i * 256 + tid;
        int d = flat >> 4, nq = (flat & 15) * 4;
        float4 v = *(const float4*)&Q[(size_t)(d0 + d) * KN + n0 + nq];
        T[d][nq] = v.x; T[d][nq + 1] = v.y; T[d][nq + 2] = v.z; T[d][nq + 3] = v.w;
    }
    __syncthreads();
    int n = tid >> 2, dbase = (tid & 3) * 16;
    unsigned u[8];
    #pragma unroll
    for (int j = 0; j < 8; ++j) {
        unsigned short a = f2bf(T[dbase + 2 * j][n]);
        unsigned short b = f2bf(T[dbase + 2 * j + 1][n]);
        u[j] = (unsigned)a | ((unsigned)b << 16);
    }
    unsigned short* o = &Qt[(size_t)(n0 + n) * DN + d0 + dbase];
    *(uint4*)o = make_uint4(u[0], u[1], u[2], u[3]);
    *(uint4*)(o + 8) = make_uint4(u[4], u[5], u[6], u[7]);
}

// ---- MFMA GEMM, swapped operands, LDS-transposed coalesced epilogue.
// Blocks with blockIdx.y >= mBlockSplit apply exp(10x) and accumulate row sums.
__global__ void __launch_bounds__(256) gemm_sim(const unsigned short* __restrict__ A,
                                                const unsigned short* __restrict__ Bt,
                                                unsigned short* __restrict__ simOut,
                                                unsigned short* __restrict__ expOut,
                                                float* __restrict__ Zb,
                                                int mBlockSplit) {
    __shared__ unsigned short smem[128 * 64 * 2];   // As | Bs, reused as epilogue buf
    __shared__ float Zred[128];
    unsigned short* As = smem;
    unsigned short* Bs = smem + 128 * 64;
    int tid = threadIdx.x;
    int n0 = blockIdx.x * 128, m0 = blockIdx.y * 128;
    bool isExp = ((int)blockIdx.y >= mBlockSplit);
    int lane = tid & 63, w = tid >> 6;
    int l15 = lane & 15, quad = lane >> 4;
    int wm = w & 1, wn = w >> 1;
    f32x4 acc[4][4];   // [mi][ni]; D layout: col(l15)=m, row(quad*4+reg)=n
    #pragma unroll
    for (int mi = 0; mi < 4; ++mi)
        #pragma unroll
        for (int ni = 0; ni < 4; ++ni)
            #pragma unroll
            for (int j = 0; j < 4; ++j) acc[mi][ni][j] = 0.f;

    for (int k0 = 0; k0 < DN; k0 += 64) {
        #pragma unroll
        for (int i = 0; i < 4; ++i) {
            int f = (i * 256 + tid) * 8;
            async16(A + (size_t)(m0 + (f >> 6)) * DN + k0 + (f & 63), &As[f]);
        }
        #pragma unroll
        for (int i = 0; i < 4; ++i) {
            int f = (i * 256 + tid) * 8;
            async16(Bt + (size_t)(n0 + (f >> 6)) * DN + k0 + (f & 63), &Bs[f]);
        }
        __syncthreads();
        #pragma unroll
        for (int ks = 0; ks < 2; ++ks) {
            bf16x8 am[4], bn[4];
            #pragma unroll
            for (int mi = 0; mi < 4; ++mi)
                am[mi] = *(const bf16x8*)&As[(wm * 64 + mi * 16 + l15) * 64 + ks * 32 + quad * 8];
            #pragma unroll
            for (int ni = 0; ni < 4; ++ni)
                bn[ni] = *(const bf16x8*)&Bs[(wn * 64 + ni * 16 + l15) * 64 + ks * 32 + quad * 8];
            #pragma unroll
            for (int mi = 0; mi < 4; ++mi)
                #pragma unroll
                for (int ni = 0; ni < 4; ++ni)
                    acc[mi][ni] = __builtin_amdgcn_mfma_f32_16x16x32_bf16(bn[ni], am[mi], acc[mi][ni], 0, 0, 0);
        }
        __syncthreads();
    }

    unsigned short* obase = isExp ? expOut : simOut;
    int orow0 = isExp ? (m0 - mBlockSplit * 128) : m0;
    float rsum[4] = {0.f, 0.f, 0.f, 0.f};

    // two rounds of 64 rows each through padded LDS, then coalesced 16B stores
    #pragma unroll
    for (int round = 0; round < 2; ++round) {
        if (wm == round) {
            #pragma unroll
            for (int mi = 0; mi < 4; ++mi) {
                int mrow = mi * 16 + l15;   // within round
                #pragma unroll
                for (int ni = 0; ni < 4; ++ni) {
                    int nc = wn * 64 + ni * 16 + quad * 4;
                    float v0 = acc[mi][ni][0], v1 = acc[mi][ni][1];
                    float v2 = acc[mi][ni][2], v3 = acc[mi][ni][3];
                    if (isExp) {
                        v0 = __expf(v0 * 10.0f); v1 = __expf(v1 * 10.0f);
                        v2 = __expf(v2 * 10.0f); v3 = __expf(v3 * 10.0f);
                    }
                    unsigned short u0 = f2bf(v0), u1 = f2bf(v1), u2 = f2bf(v2), u3 = f2bf(v3);
                    if (isExp) rsum[mi] += bf2f(u0) + bf2f(u1) + bf2f(u2) + bf2f(u3);
                    *(uint2*)&smem[mrow * EPSTR + nc] =
                        make_uint2((unsigned)u0 | ((unsigned)u1 << 16),
                                   (unsigned)u2 | ((unsigned)u3 << 16));
                }
            }
        }
        __syncthreads();
        #pragma unroll
        for (int j = 0; j < 4; ++j) {
            int fc = j * 256 + tid;          // 0..1023
            int mr = fc >> 4;                // 0..63
            int ch = fc & 15;                // 16-byte chunk within row
            uint4 val = *(uint4*)&smem[mr * EPSTR + ch * 8];
            int g = orow0 + round * 64 + mr;
            *(uint4*)&obase[(size_t)g * KN + n0 + ch * 8] = val;
        }
        __syncthreads();
    }

    if (isExp) {
        float v4[4];
        #pragma unroll
        for (int mi = 0; mi < 4; ++mi) {
            float v = rsum[mi];
            v += __shfl_xor(v, 16, 64);
            v += __shfl_xor(v, 32, 64);
            v4[mi] = v;
        }
        if (wn == 0 && quad == 0) {
            #pragma unroll
            for (int mi = 0; mi < 4; ++mi) Zred[wm * 64 + mi * 16 + l15] = v4[mi];
        }
        __syncthreads();
        if (wn == 1 && quad == 0) {
            #pragma unroll
            for (int mi = 0; mi < 4; ++mi) Zred[wm * 64 + mi * 16 + l15] += v4[mi];
        }
        __syncthreads();
        if (tid < 128) atomicAdd(&Zb[orow0 + tid], Zred[tid]);
    }
}

// ---- supcon on bf16 sim: 2-pass radix select over 16-bit keys + fused loss ----
__global__ void __launch_bounds__(256) supcon(const unsigned short* __restrict__ sim,
                                              const int* __restrict__ qlabel,
                                              const int* __restrict__ target,
                                              const int* __restrict__ knnp,
                                              float* __restrict__ out0) {
    __shared__ unsigned hist[4][256];
    __shared__ unsigned s_sel, s_cntAbove;
    __shared__ int eqIdx[EQ_CAP];
    __shared__ unsigned eqCount;
    __shared__ float redZ[256], redN[256];
    int tid = threadIdx.x, w = tid >> 6;
    int row = blockIdx.x;
    const unsigned short* srow = sim + (size_t)row * KN;
    int knn = *knnp;
    int tgt = target[row];
    if (tid == 0) { eqCount = 0u; }
    #pragma unroll
    for (int j = 0; j < 4; ++j) hist[j][tid] = 0u;
    __syncthreads();
    for (int i0 = tid * 4; i0 < KN; i0 += 1024) {
        uint2 v = *(const uint2*)&srow[i0];
        atomicAdd(&hist[w][fkey16(v.x) >> 8], 1u);
        atomicAdd(&hist[w][fkey16(v.x >> 16) >> 8], 1u);
        atomicAdd(&hist[w][fkey16(v.y) >> 8], 1u);
        atomicAdd(&hist[w][fkey16(v.y >> 16) >> 8], 1u);
    }
    __syncthreads();
    if (tid == 0) {
        unsigned acc = 0; int chosen = 0;
        for (int bin = 255; bin >= 0; --bin) {
            unsigned h = hist[0][bin] + hist[1][bin] + hist[2][bin] + hist[3][bin];
            if (acc + h >= (unsigned)knn) { chosen = bin; break; }
            acc += h;
        }
        s_cntAbove = acc; s_sel = (unsigned)chosen;
    }
    __syncthreads();
    unsigned selHi = s_sel;
    #pragma unroll
    for (int j = 0; j < 4; ++j) hist[j][tid] = 0u;
    __syncthreads();
    for (int i0 = tid * 4; i0 < KN; i0 += 1024) {
        uint2 v = *(const uint2*)&srow[i0];
        unsigned k0 = fkey16(v.x), k1 = fkey16(v.x >> 16), k2 = fkey16(v.y), k3 = fkey16(v.y >> 16);
        if ((k0 >> 8) == selHi) atomicAdd(&hist[w][k0 & 255u], 1u);
        if ((k1 >> 8) == selHi) atomicAdd(&hist[w][k1 & 255u], 1u);
        if ((k2 >> 8) == selHi) atomicAdd(&hist[w][k2 & 255u], 1u);
        if ((k3 >> 8) == selHi) atomicAdd(&hist[w][k3 & 255u], 1u);
    }
    __syncthreads();
    if (tid == 0) {
        unsigned acc = s_cntAbove; int chosen = 0;
        for (int bin = 255; bin >= 0; --bin) {
            unsigned h = hist[0][bin] + hist[1][bin] + hist[2][bin] + hist[3][bin];
            if (acc + h >= (unsigned)knn) { chosen = bin; break; }
            acc += h;
        }
        s_cntAbove = acc; s_sel = (selHi << 8) | (unsigned)chosen;
    }
    __syncthreads();
    unsigned tu = s_sel;
    unsigned cgt = s_cntAbove;
    const float invT = 1.0f / 0.07f;
    float Zl = 0.f, Nl = 0.f;
    for (int i0 = tid * 4; i0 < KN; i0 += 1024) {
        uint2 v = *(const uint2*)&srow[i0];
        unsigned bits[4] = {v.x & 0xFFFFu, v.x >> 16, v.y & 0xFFFFu, v.y >> 16};
        #pragma unroll
        for (int j = 0; j < 4; ++j) {
            unsigned u = fkey16(bits[j]);
            if (u > tu) {
                float e = __expf(bf2f((unsigned short)bits[j]) * invT);
                Zl += e;
                if (qlabel[i0 + j] == tgt) Nl += e;
            } else if (u == tu) {
                unsigned pos = atomicAdd(&eqCount, 1u);
                if (pos < EQ_CAP) eqIdx[pos] = i0 + j;
            }
        }
    }
    redZ[tid] = Zl; redN[tid] = Nl;
    __syncthreads();
    for (int s = 128; s > 0; s >>= 1) {
        if (tid < s) { redZ[tid] += redZ[tid + s]; redN[tid] += redN[tid + s]; }
        __syncthreads();
    }
    if (tid == 0) {
        float Z = redZ[0], num = redN[0];
        int neq = (int)(eqCount < (unsigned)EQ_CAP ? eqCount : (unsigned)EQ_CAP);
        int needed = knn - (int)cgt;
        if (needed > neq) needed = neq;
        for (int a = 1; a < neq; ++a) {
            int v = eqIdx[a]; int b2 = a - 1;
            while (b2 >= 0 && eqIdx[b2] > v) { eqIdx[b2 + 1] = eqIdx[b2]; --b2; }
            eqIdx[b2 + 1] = v;
        }
        unsigned tb = (tu & 0x8000u) ? (tu & 0x7FFFu) : ((~tu) & 0xFFFFu);
        float wt = __expf(bf2f((unsigned short)tb) * invT);
        for (int a = 0; a < needed; ++a) {
            Z += wt;
            if (qlabel[eqIdx[a]] == tgt) num += wt;
        }
        float gt = num / Z;
        if (gt > 1e-8f) atomicAdd(out0, -logf(gt) * (1.0f / (float)BN));
    }
}

// ---- dc gemm: E[512,65536]bf16 @ qlp[1000,65536]f32(->bf16) ^T, split-k=16 ----
__global__ void __launch_bounds__(256) dc_gemm(const unsigned short* __restrict__ E,
                                               const float* __restrict__ P,
                                               float* __restrict__ dct) {
    __shared__ unsigned short As[128 * 32];
    __shared__ unsigned short Bs[128 * 32];
    int tid = threadIdx.x;
    int c0 = blockIdx.x * 128, m0 = blockIdx.y * 128;
    int kb = blockIdx.z * (KN / 16);
    int lane = tid & 63, w = tid >> 6;
    int l15 = lane & 15, quad = lane >> 4;
    int wm = w & 1, wn = w >> 1;
    int crow = tid >> 1, khalf = (tid & 1) * 16;
    bool cvalid = (c0 + crow) < CN;
    const float* pbase = P + (size_t)(c0 + crow) * KN + khalf;
    f32x4 acc[4][4];
    #pragma unroll
    for (int r = 0; r < 4; ++r)
        #pragma unroll
        for (int c = 0; c < 4; ++c)
            #pragma unroll
            for (int j = 0; j < 4; ++j) acc[r][c][j] = 0.f;
    for (int kc = 0; kc < KN / 16; kc += 32) {
        int k0 = kb + kc;
        #pragma unroll
        for (int i = 0; i < 2; ++i) {
            int flat = (i * 256 + tid) * 8;
            int row = flat >> 5, kk = flat & 31;
            async16(E + (size_t)(m0 + row) * KN + k0 + kk, &As[flat]);
        }
        float4 p0 = make_float4(0.f, 0.f, 0.f, 0.f), p1 = p0, p2 = p0, p3 = p0;
        if (cvalid) {
            p0 = *(const float4*)&pbase[k0];
            p1 = *(const float4*)&pbase[k0 + 4];
            p2 = *(const float4*)&pbase[k0 + 8];
            p3 = *(const float4*)&pbase[k0 + 12];
        }
        unsigned u0 = (unsigned)f2bf(p0.x) | ((unsigned)f2bf(p0.y) << 16);
        unsigned u1 = (unsigned)f2bf(p0.z) | ((unsigned)f2bf(p0.w) << 16);
        unsigned u2 = (unsigned)f2bf(p1.x) | ((unsigned)f2bf(p1.y) << 16);
        unsigned u3 = (unsigned)f2bf(p1.z) | ((unsigned)f2bf(p1.w) << 16);
        unsigned u4 = (unsigned)f2bf(p2.x) | ((unsigned)f2bf(p2.y) << 16);
        unsigned u5 = (unsigned)f2bf(p2.z) | ((unsigned)f2bf(p2.w) << 16);
        unsigned u6 = (unsigned)f2bf(p3.x) | ((unsigned)f2bf(p3.y) << 16);
        unsigned u7 = (unsigned)f2bf(p3.z) | ((unsigned)f2bf(p3.w) << 16);
        *(uint4*)&Bs[crow * 32 + khalf] = make_uint4(u0, u1, u2, u3);
        *(uint4*)&Bs[crow * 32 + khalf + 8] = make_uint4(u4, u5, u6, u7);
        __syncthreads();
        bf16x8 af[4], bfr[4];
        #pragma unroll
        for (int r = 0; r < 4; ++r) af[r] = *(const bf16x8*)&As[(wm * 64 + r * 16 + l15) * 32 + quad * 8];
        #pragma unroll
        for (int c = 0; c < 4; ++c) bfr[c] = *(const bf16x8*)&Bs[(wn * 64 + c * 16 + l15) * 32 + quad * 8];
        #pragma unroll
        for (int r = 0; r < 4; ++r)
            #pragma unroll
            for (int c = 0; c < 4; ++c)
                acc[r][c] = __builtin_amdgcn_mfma_f32_16x16x32_bf16(af[r], bfr[c], acc[r][c], 0, 0, 0);
        __syncthreads();
    }
    #pragma unroll
    for (int r = 0; r < 4; ++r)
        #pragma unroll
        for (int reg = 0; reg < 4; ++reg) {
            int m = m0 + wm * 64 + r * 16 + quad * 4 + reg;
            #pragma unroll
            for (int c = 0; c < 4; ++c) {
                int cc = c0 + wn * 64 + c * 16 + l15;
                atomicAdd(&dct[m * 1024 + cc], acc[r][c][reg]);
            }
        }
}

// ---- log_softmax(q_logits), qmask, fc loss ----
__global__ void __launch_bounds__(256) logq_fc(const float* __restrict__ x_all,
                                               const int* __restrict__ target,
                                               float* __restrict__ logq,
                                               float* __restrict__ qmask,
                                               float* __restrict__ out1) {
    int row = blockIdx.x, tid = threadIdx.x;
    const float* x = x_all + (size_t)row * CN;
    __shared__ float red[256], red2[256];
    float mx = -INFINITY, mn = INFINITY;
    for (int c = tid; c < CN; c += 256) { float v = x[c]; mx = fmaxf(mx, v); mn = fminf(mn, v); }
    red[tid] = mx; red2[tid] = mn;
    __syncthreads();
    for (int s = 128; s > 0; s >>= 1) {
        if (tid < s) { red[tid] = fmaxf(red[tid], red[tid + s]); red2[tid] = fminf(red2[tid], red2[tid + s]); }
        __syncthreads();
    }
    mx = red[0]; mn = red2[0];
    __syncthreads();
    float se = 0.f, sx = 0.f;
    for (int c = tid; c < CN; c += 256) { float v = x[c]; se += __expf(v - mx); sx += v; }
    red[tid] = se; red2[tid] = sx;
    __syncthreads();
    for (int s = 128; s > 0; s >>= 1) {
        if (tid < s) { red[tid] += red[tid + s]; red2[tid] += red2[tid + s]; }
        __syncthreads();
    }
    float lse = mx + logf(red[0]);
    float sumlogq = red2[0] - (float)CN * lse;
    for (int c = tid; c < CN; c += 256) logq[(size_t)row * CN + c] = x[c] - lse;
    if (tid == 0) {
        float lqt = x[target[row]] - lse;
        bool qm = (mn - lse) > logf(1e-8f);
        qmask[row] = qm ? 1.0f : 0.0f;
        if (qm) {
            float fc = -(0.1f / 999.0f * (sumlogq - lqt) + 0.9f * lqt);
            atomicAdd(out1, fc * (1.0f / (float)BN));
        }
    }
}

// ---- dc loss ----
__global__ void __launch_bounds__(256) dc_loss(const float* __restrict__ dct,
                                               const float* __restrict__ logq,
                                               const float* __restrict__ qmask,
                                               const float* __restrict__ Z,
                                               float* __restrict__ out2) {
    int row = blockIdx.x, tid = threadIdx.x;
    __shared__ float red[256];
    float invZ = 1.0f / Z[row];
    float s = 0.f;
    for (int c = tid; c < CN; c += 256) {
        float T = dct[row * 1024 + c] * invZ;
        if (T > 0.f) s += T * (logf(T) - logq[(size_t)row * CN + c]);
    }
    red[tid] = s;
    __syncthreads();
    for (int st = 128; st > 0; st >>= 1) {
        if (tid < st) red[tid] += red[tid + st];
        __syncthreads();
    }
    if (tid == 0 && qmask[row] > 0.f)
        atomicAdd(out2, red[0] * (1.0f / (float)BN));
}

extern "C" void kernel_launch(void* const* d_in, const int* in_sizes, int n_in,
                              void* d_out, int out_size, void* d_ws, size_t ws_size,
                              hipStream_t stream) {
    (void)in_sizes; (void)n_in; (void)out_size;
    const float* norm_q   = (const float*)d_in[0];
    const float* q_logits = (const float*)d_in[1];
    const float* k_feat   = (const float*)d_in[2];
    const float* queue    = (const float*)d_in[4];
    const float* qlp      = (const float*)d_in[5];
    const int*   qlabel   = (const int*)d_in[6];
    const int*   target   = (const int*)d_in[7];
    const int*   knnp     = (const int*)d_in[8];
    float* out = (float*)d_out;
    char* ws = (char*)d_ws;

    const size_t SIM_B = 67108864;     // 512*65536*2
    const size_t QT_B  = 33554432;     // 65536*256*2
    const size_t AC_B  = 524288;       // 1024*256*2
    const size_t FUSED_NEED = SIM_B * 2 + QT_B + AC_B + 2097152 + 2048 + 2048000 + 2048;
    bool fused = (ws_size >= FUSED_NEED);

    unsigned short *simBF, *Ebf, *queueT, *Acat;
    float *dct, *Zb, *logq, *qmask;
    if (fused) {
        simBF  = (unsigned short*)(ws);
        Ebf    = (unsigned short*)(ws + SIM_B);
        queueT = (unsigned short*)(ws + 2 * SIM_B);
        Acat   = (unsigned short*)(ws + 2 * SIM_B + QT_B);
        dct    = (float*)(ws + 2 * SIM_B + QT_B + AC_B);
    } else {
        simBF  = (unsigned short*)(ws);
        Ebf    = simBF;   // overlay: supcon consumes simBF before E is written
        queueT = (unsigned short*)(ws + SIM_B);
        Acat   = (unsigned short*)(ws + SIM_B + QT_B);
        dct    = (float*)(ws + SIM_B + QT_B + AC_B);
    }
    Zb    = (float*)((char*)dct + 2097152);
    logq  = (float*)((char*)Zb + 2048);
    qmask = (float*)((char*)logq + 2048000);

    hipMemsetAsync(dct, 0, 2097152 + 2048, stream);   // dct + Zb
    hipMemsetAsync(d_out, 0, 3 * sizeof(float), stream);

    cvt_bf16<<<dim3(128), 256, 0, stream>>>(norm_q, Acat);
    cvt_bf16<<<dim3(128), 256, 0, stream>>>(k_feat, Acat + (size_t)BN * DN);
    transpose_q<<<dim3(KN / 64, 4), 256, 0, stream>>>(queue, queueT);

    if (fused) {
        gemm_sim<<<dim3(KN / 128, 8), 256, 0, stream>>>(Acat, queueT, simBF, Ebf, Zb, 4);
        supcon<<<dim3(BN), 256, 0, stream>>>(simBF, qlabel, target, knnp, out + 0);
    } else {
        gemm_sim<<<dim3(KN / 128, 4), 256, 0, stream>>>(Acat, queueT, simBF, nullptr, nullptr, 4);
        supcon<<<dim3(BN), 256, 0, stream>>>(simBF, qlabel, target, knnp, out + 0);
        gemm_sim<<<dim3(KN / 128, 4), 256, 0, stream>>>(Acat + (size_t)BN * DN, queueT,
                                                        nullptr, Ebf, Zb, 0);
    }
    dc_gemm<<<dim3(8, 4, 16), 256, 0, stream>>>(Ebf, qlp, dct);
    logq_fc<<<dim3(BN), 256, 0, stream>>>(q_logits, target, logq, qmask, out + 1);
    dc_loss<<<dim3(BN), 256, 0, stream>>>(dct, logq, qmask, Zb, out + 2);
}